// Round 6
// baseline (253.532 us; speedup 1.0000x reference)
//
#include <hip/hip_runtime.h>

#define NB 32
#define NP 24564
#define NO 50
#define NC 81
#define THR 0.5f

// ---------------- Kernel 0: zero-init header -------------------------------
__global__ __launch_bounds__(256) void k0(
    double* __restrict__ acc, int* __restrict__ num_pos,
    float* __restrict__ accLb, float* __restrict__ accCb,
    unsigned long long* __restrict__ bp) {
  const int tid = threadIdx.x;
  if (tid < 4) acc[tid] = 0.0;
  if (tid < NB) { num_pos[tid] = 0; accLb[tid] = 0.0f; accCb[tid] = 0.0f; }
  for (int i = tid; i < NB * NO; i += 256) bp[i] = 0ull;
}

// ---------------- Kernel A: per-truth best prior ---------------------------
#define KA_CHUNK 2048

__global__ __launch_bounds__(256) void kA(
    const float* __restrict__ priors, const float* __restrict__ targets,
    unsigned long long* __restrict__ bp_packed) {
  __shared__ float4 s_pf[KA_CHUNK];
  __shared__ float s_t[NO * 5];
  const int b = blockIdx.y;
  const int tid = threadIdx.x;
  const int base = blockIdx.x * KA_CHUNK;

  for (int i = tid; i < NO * 5; i += 256) s_t[i] = targets[b * NO * 5 + i];

  #pragma unroll
  for (int k = 0; k < KA_CHUNK / 256; ++k) {
    const int p = base + k * 256 + tid;
    float4 pf;
    if (p < NP) {
      const float4 pr = ((const float4*)priors)[p];
      pf = make_float4(pr.x - pr.z * 0.5f, pr.y - pr.w * 0.5f,
                       pr.x + pr.z * 0.5f, pr.y + pr.w * 0.5f);
    } else {
      pf = make_float4(3.0f, 3.0f, 3.0f, 3.0f);  // degenerate: IoU == 0
    }
    s_pf[k * 256 + tid] = pf;
  }
  __syncthreads();

  const int wv = tid >> 6;
  const int lane = tid & 63;
  if (lane < NO) {
    const float tx1 = s_t[lane * 5 + 0], ty1 = s_t[lane * 5 + 1];
    const float tx2 = s_t[lane * 5 + 2], ty2 = s_t[lane * 5 + 3];
    const float area_a = (tx2 - tx1) * (ty2 - ty1);
    const int i0 = wv * (KA_CHUNK / 4);
    unsigned long long best = 0ull;
    #pragma unroll 8
    for (int i = 0; i < KA_CHUNK / 4; ++i) {
      const float4 q = s_pf[i0 + i];
      const float ltx = fmaxf(tx1, q.x), lty = fmaxf(ty1, q.y);
      const float rbx = fminf(tx2, q.z), rby = fminf(ty2, q.w);
      const float wx = fmaxf(rbx - ltx, 0.0f), wy = fmaxf(rby - lty, 0.0f);
      const float inter = wx * wy;
      const float ab = (q.z - q.x) * (q.w - q.y);
      const float iou = __fdividef(inter, area_a + ab - inter);
      const unsigned p = (unsigned)(base + i0 + i);
      const unsigned long long pk =
          (((unsigned long long)__float_as_uint(iou)) << 32) |
          (unsigned long long)(0xFFFFFFFFu - p);
      if (pk > best) best = pk;
    }
    atomicMax(&bp_packed[b * NO + lane], best);
  }
}

// ---------------- Kernel C: lane-per-row, DMA-staged conf ------------------
// grid = (24, NB), 64 threads (1 wave). Block covers 16 tiles x 64 rows.
// conf tile (64 rows x 81 f32 = 20736 B, contiguous) staged via
// global_load_lds width 16, double-buffered; no barriers (single wave).
#define KC_TILES 16
#define KC_CH 21                 // 21 x 1024 B chunks per tile (21504 B)
#define KC_BUF 5376              // floats per buffer (21*256)

__global__ __launch_bounds__(64) void kC(
    const float* __restrict__ loc, const float* __restrict__ conf,
    const float* __restrict__ priors, const float* __restrict__ targets,
    const unsigned* __restrict__ bp32,   // low dwords of bp_packed (LE)
    float* __restrict__ mine, int* __restrict__ num_pos,
    float* __restrict__ accLb, float* __restrict__ accCb) {
  __shared__ float s_conf[2][KC_BUF];
  const int lane = threadIdx.x;
  const int b = blockIdx.y;
  const int block_row0 = blockIdx.x * (KC_TILES * 64);
  const size_t total_dw = (size_t)NB * NP * NC;
  const size_t max_dw = total_dw - 4;
  const unsigned* confu = (const unsigned*)conf;
  const float* tb = targets + (size_t)b * (NO * 5);

  float sumL = 0.0f, sumC = 0.0f;
  int cnt = 0;

  // ---- stage tile t into buffer buf (async DMA, linear lane order) --------
  auto stage = [&](int buf, int t) {
    const size_t tile_dw =
        ((size_t)b * NP + (size_t)(block_row0 + t * 64)) * NC;
    const bool oob = (tile_dw + (size_t)KC_CH * 256) > total_dw;
    #pragma unroll
    for (int k = 0; k < KC_CH; ++k) {
      size_t idx = tile_dw + (size_t)(k * 256 + lane * 4);
      if (oob && idx > max_dw) idx = max_dw;  // 4-dw aligned clamp
      __builtin_amdgcn_global_load_lds(
          (const __attribute__((address_space(1))) unsigned*)(confu + idx),
          (__attribute__((address_space(3))) unsigned*)(&s_conf[buf][k * 256]),
          16, 0, 0);
    }
  };

  stage(0, 0);
  int cur = 0;

  #pragma unroll 1
  for (int t = 0; t < KC_TILES; ++t) {
    asm volatile("s_waitcnt vmcnt(0)" ::: "memory");
    if (t + 1 < KC_TILES) stage(cur ^ 1, t + 1);

    const int p = block_row0 + t * 64 + lane;
    const bool valid = (p < NP);
    const int pp = valid ? p : (NP - 1);
    const float4 pr = ((const float4*)priors)[pp];
    const float px1 = pr.x - pr.z * 0.5f, py1 = pr.y - pr.w * 0.5f;
    const float px2 = pr.x + pr.z * 0.5f, py2 = pr.y + pr.w * 0.5f;
    const float areab = (px2 - px1) * (py2 - py1);

    // ---- lane-local match over 50 truths (uniform SMEM reads) ------------
    float bv = -1.0f;
    int bj = 0, ovj = -1;
    #pragma unroll 2
    for (int j = 0; j < NO; ++j) {
      const float tx1 = tb[j * 5 + 0], ty1 = tb[j * 5 + 1];
      const float tx2 = tb[j * 5 + 2], ty2 = tb[j * 5 + 3];
      const float ltx = fmaxf(tx1, px1), lty = fmaxf(ty1, py1);
      const float rbx = fminf(tx2, px2), rby = fminf(ty2, py2);
      const float wx = fmaxf(rbx - ltx, 0.0f), wy = fmaxf(rby - lty, 0.0f);
      const float inter = wx * wy;
      const float area_a = (tx2 - tx1) * (ty2 - ty1);
      const float iou = __fdividef(inter, area_a + areab - inter);
      if (iou > bv) { bv = iou; bj = j; }   // first-max tie-break
      const unsigned pbest = 0xFFFFFFFFu - bp32[(b * NO + j) * 2];
      if (pbest == (unsigned)p) ovj = j;    // ascending j -> last wins
    }
    const int j = (ovj >= 0) ? ovj : bj;
    const float lab = tb[j * 5 + 4];
    const int conft = (ovj < 0 && bv < THR) ? 0 : ((int)lab + 1);

    // ---- row lse + gather from LDS (thread-local) ------------------------
    const float* rowp = &s_conf[cur][lane * NC];
    float s0 = 0.0f, s1 = 0.0f, s2 = 0.0f, s3 = 0.0f;
    #pragma unroll
    for (int c = 0; c < 80; c += 4) {
      s0 += __expf(rowp[c + 0]);
      s1 += __expf(rowp[c + 1]);
      s2 += __expf(rowp[c + 2]);
      s3 += __expf(rowp[c + 3]);
    }
    const float s = ((s0 + s1) + (s2 + s3)) + __expf(rowp[80]);
    const float gval = rowp[conft];
    const float lca = __logf(s) - gval;
    const bool pos = (conft > 0);

    if (valid) {
      mine[(size_t)b * NP + p] = pos ? 0.0f : fmaxf(lca, 0.0f);
      if (pos) {
        cnt++;
        sumC += lca;
        const float mx1 = tb[j * 5 + 0], my1 = tb[j * 5 + 1];
        const float mx2 = tb[j * 5 + 2], my2 = tb[j * 5 + 3];
        const float gcx = __fdividef((mx1 + mx2) * 0.5f - pr.x, 0.1f * pr.z);
        const float gcy = __fdividef((my1 + my2) * 0.5f - pr.y, 0.1f * pr.w);
        const float gw = __logf(__fdividef(mx2 - mx1, pr.z)) * 5.0f;
        const float gh = __logf(__fdividef(my2 - my1, pr.w)) * 5.0f;
        const float4 ld = ((const float4*)loc)[(size_t)b * NP + p];
        const float d0 = ld.x - gcx, d1 = ld.y - gcy;
        const float d2 = ld.z - gw, d3 = ld.w - gh;
        float sm = 0.0f;
        #pragma unroll
        for (int q = 0; q < 4; ++q) {
          const float d = (q == 0) ? d0 : (q == 1) ? d1 : (q == 2) ? d2 : d3;
          const float a = fabsf(d);
          sm += (a < 1.0f) ? 0.5f * d * d : a - 0.5f;
        }
        sumL += sm;
      }
    }
    cur ^= 1;
  }

  // ---- single wave reduce + one atomic set per block -----------------------
  #pragma unroll
  for (int m = 1; m <= 32; m <<= 1) {
    sumL += __shfl_xor(sumL, m, 64);
    sumC += __shfl_xor(sumC, m, 64);
    cnt  += __shfl_xor(cnt, m, 64);
  }
  if (lane == 0) {
    if (sumL != 0.0f) atomicAdd(&accLb[b], sumL);
    if (sumC != 0.0f) atomicAdd(&accCb[b], sumC);
    if (cnt) atomicAdd(&num_pos[b], cnt);
  }
}

// ---------------- Kernel D: exact top-K sum via bitwise radix select -------
__global__ __launch_bounds__(512) void kD(
    const float* __restrict__ mine, const int* __restrict__ num_pos,
    double* __restrict__ acc) {
  const int b = blockIdx.x;
  const int tid = threadIdx.x;
  const float* vb = mine + (size_t)b * NP;

  unsigned vals[48];
  #pragma unroll
  for (int k = 0; k < 48; ++k) {
    const int i = tid + k * 512;
    vals[k] = (i < NP) ? __float_as_uint(vb[i]) : 0u;
  }

  const int K = min(3 * num_pos[b], NP - 1);

  __shared__ int s_w[2][8];
  unsigned prefix = 0u;
  int remaining = K;

  for (int bit = 30; bit >= 0; --bit) {
    const unsigned want = (prefix >> bit) | 1u;
    int cnt = 0;
    #pragma unroll
    for (int k = 0; k < 48; ++k) cnt += ((vals[k] >> bit) == want) ? 1 : 0;
    #pragma unroll
    for (int m = 32; m >= 1; m >>= 1) cnt += __shfl_xor(cnt, m, 64);
    const int buf = bit & 1;
    if ((tid & 63) == 0) s_w[buf][tid >> 6] = cnt;
    __syncthreads();
    int total = 0;
    #pragma unroll
    for (int w = 0; w < 8; ++w) total += s_w[buf][w];
    if (total >= remaining) prefix |= (1u << bit);
    else remaining -= total;
  }

  if (K > 0) {
    const float t = __uint_as_float(prefix);
    double sg = 0.0;
    int cg = 0;
    #pragma unroll
    for (int k = 0; k < 48; ++k) {
      const float f = __uint_as_float(vals[k]);
      if (f > t) { sg += (double)f; cg++; }
    }
    #pragma unroll
    for (int m = 32; m >= 1; m >>= 1) {
      sg += __shfl_xor(sg, m, 64);
      cg += __shfl_xor(cg, m, 64);
    }
    __shared__ double s_sd[8];
    __shared__ int s_sc[8];
    const int wid = tid >> 6;
    if ((tid & 63) == 0) { s_sd[wid] = sg; s_sc[wid] = cg; }
    __syncthreads();
    if (tid == 0) {
      double S = 0.0;
      int C = 0;
      for (int w = 0; w < 8; ++w) { S += s_sd[w]; C += s_sc[w]; }
      S += (double)(K - C) * (double)t;
      atomicAdd(&acc[2], S);
    }
  }
}

// ---------------- Kernel E: finalize ---------------------------------------
__global__ void kE(const double* __restrict__ acc, const float* __restrict__ accLb,
                   const float* __restrict__ accCb, const int* __restrict__ num_pos,
                   float* __restrict__ out) {
  const int lane = threadIdx.x & 63;
  int n = 0;
  float L = 0.0f, C = 0.0f;
  if (lane < NB) { n = num_pos[lane]; L = accLb[lane]; C = accCb[lane]; }
  #pragma unroll
  for (int m = 32; m >= 1; m >>= 1) {
    n += __shfl_xor(n, m, 64);
    L += __shfl_xor(L, m, 64);
    C += __shfl_xor(C, m, 64);
  }
  if (lane == 0 && blockIdx.x == 0) {
    const double Nf = (double)n;
    out[0] = (float)((double)L / Nf);
    out[1] = (float)(((double)C + acc[2]) / Nf);
  }
}

extern "C" void kernel_launch(void* const* d_in, const int* in_sizes, int n_in,
                              void* d_out, int out_size, void* d_ws, size_t ws_size,
                              hipStream_t stream) {
  const float* loc     = (const float*)d_in[0];
  const float* conf    = (const float*)d_in[1];
  const float* priors  = (const float*)d_in[2];
  const float* targets = (const float*)d_in[3];
  float* out = (float*)d_out;

  char* ws = (char*)d_ws;
  double* acc   = (double*)ws;                       // 4 doubles   @ 0    (32 B)
  int* num_pos  = (int*)(ws + 32);                   // 32 ints     @ 32   (128 B)
  float* accLb  = (float*)(ws + 160);                // 32 floats   @ 160  (128 B)
  float* accCb  = (float*)(ws + 288);                // 32 floats   @ 288  (128 B)
  unsigned long long* bp = (unsigned long long*)(ws + 416);  // 1600 u64 (12800 B)
  const size_t hdr = 13216;
  float* mine  = (float*)(ws + hdr);                 // NB*NP floats

  k0<<<1, 256, 0, stream>>>(acc, num_pos, accLb, accCb, bp);

  dim3 gA((NP + KA_CHUNK - 1) / KA_CHUNK, NB);
  kA<<<gA, 256, 0, stream>>>(priors, targets, bp);

  dim3 gC(24, NB);   // 24 blocks x 1024 rows = 24576 >= NP
  kC<<<gC, 64, 0, stream>>>(loc, conf, priors, targets, (const unsigned*)bp,
                            mine, num_pos, accLb, accCb);
  kD<<<NB, 512, 0, stream>>>(mine, num_pos, acc);
  kE<<<1, 64, 0, stream>>>(acc, accLb, accCb, num_pos, out);
}

// Round 7
// 226.182 us; speedup vs baseline: 1.1209x; 1.1209x over previous
//
#include <hip/hip_runtime.h>

#define NB 32
#define NP 24564
#define NO 50
#define NC 81
#define THR 0.5f

__device__ __forceinline__ float rl_f(float v, int j) {
  return __uint_as_float((unsigned)__builtin_amdgcn_readlane((int)__float_as_uint(v), j));
}

// ---------------- Kernel 0: zero-init header -------------------------------
__global__ __launch_bounds__(256) void k0(
    double* __restrict__ acc, int* __restrict__ num_pos,
    float* __restrict__ accLb, float* __restrict__ accCb,
    unsigned long long* __restrict__ bp) {
  const int tid = threadIdx.x;
  if (tid < 4) acc[tid] = 0.0;
  if (tid < NB) { num_pos[tid] = 0; accLb[tid] = 0.0f; accCb[tid] = 0.0f; }
  for (int i = tid; i < NB * NO; i += 256) bp[i] = 0ull;
}

// ---------------- Kernel A: per-truth best prior ---------------------------
#define KA_CHUNK 2048

__global__ __launch_bounds__(256) void kA(
    const float* __restrict__ priors, const float* __restrict__ targets,
    unsigned long long* __restrict__ bp_packed) {
  __shared__ float4 s_pf[KA_CHUNK];
  __shared__ float s_t[NO * 5];
  const int b = blockIdx.y;
  const int tid = threadIdx.x;
  const int base = blockIdx.x * KA_CHUNK;

  for (int i = tid; i < NO * 5; i += 256) s_t[i] = targets[b * NO * 5 + i];

  #pragma unroll
  for (int k = 0; k < KA_CHUNK / 256; ++k) {
    const int p = base + k * 256 + tid;
    float4 pf;
    if (p < NP) {
      const float4 pr = ((const float4*)priors)[p];
      pf = make_float4(pr.x - pr.z * 0.5f, pr.y - pr.w * 0.5f,
                       pr.x + pr.z * 0.5f, pr.y + pr.w * 0.5f);
    } else {
      pf = make_float4(3.0f, 3.0f, 3.0f, 3.0f);  // degenerate: IoU == 0
    }
    s_pf[k * 256 + tid] = pf;
  }
  __syncthreads();

  const int wv = tid >> 6;
  const int lane = tid & 63;
  if (lane < NO) {
    const float tx1 = s_t[lane * 5 + 0], ty1 = s_t[lane * 5 + 1];
    const float tx2 = s_t[lane * 5 + 2], ty2 = s_t[lane * 5 + 3];
    const float area_a = (tx2 - tx1) * (ty2 - ty1);
    const int i0 = wv * (KA_CHUNK / 4);
    unsigned long long best = 0ull;
    #pragma unroll 8
    for (int i = 0; i < KA_CHUNK / 4; ++i) {
      const float4 q = s_pf[i0 + i];
      const float ltx = fmaxf(tx1, q.x), lty = fmaxf(ty1, q.y);
      const float rbx = fminf(tx2, q.z), rby = fminf(ty2, q.w);
      const float wx = fmaxf(rbx - ltx, 0.0f), wy = fmaxf(rby - lty, 0.0f);
      const float inter = wx * wy;
      const float ab = (q.z - q.x) * (q.w - q.y);
      const float iou = __fdividef(inter, area_a + ab - inter);
      const unsigned p = (unsigned)(base + i0 + i);
      const unsigned long long pk =
          (((unsigned long long)__float_as_uint(iou)) << 32) |
          (unsigned long long)(0xFFFFFFFFu - p);
      if (pk > best) best = pk;
    }
    atomicMax(&bp_packed[b * NO + lane], best);
  }
}

// ---------------- Kernel C: lane-per-row, DMA conf, register truths --------
// grid = (24, NB), 64 threads (1 wave). 16 tiles x 64 rows per block.
// Truths live in lane-registers (lane l -> truth l), broadcast per j via
// readlane: the match loop touches NO memory. conf staged via
// global_load_lds (w16), double-buffered, no barriers (single wave).
#define KC_ROWS 64
#define KC_TPB 16
#define KC_CH 21                 // ceil(64*81/256) chunks of 1 KB
#define KC_BUFDW (KC_CH * 256)   // 5376 dwords per buffer

__global__ __launch_bounds__(64) void kC(
    const float* __restrict__ loc, const float* __restrict__ conf,
    const float* __restrict__ priors, const float* __restrict__ targets,
    const unsigned* __restrict__ bp32,   // low dwords of bp_packed (LE)
    float* __restrict__ mine, int* __restrict__ num_pos,
    float* __restrict__ accLb, float* __restrict__ accCb) {
  __shared__ float s_conf[2][KC_BUFDW];
  __shared__ float s_t[NO * 5];
  const int lane = threadIdx.x;
  const int b = blockIdx.y;
  const int block_row0 = blockIdx.x * (KC_TPB * KC_ROWS);
  const size_t total_dw = (size_t)NB * NP * NC;
  const size_t max_dw = total_dw - 4;
  const unsigned* confu = (const unsigned*)conf;
  const float* tb = targets + (size_t)b * (NO * 5);

  for (int i = lane; i < NO * 5; i += 64) s_t[i] = tb[i];

  // lane l holds truth l entirely in registers
  float ttx1 = 3.0f, tty1 = 3.0f, ttx2 = 3.0f, tty2 = 3.0f, tar = 0.0f;
  int tpb = -1;
  if (lane < NO) {
    ttx1 = tb[lane * 5 + 0]; tty1 = tb[lane * 5 + 1];
    ttx2 = tb[lane * 5 + 2]; tty2 = tb[lane * 5 + 3];
    tar = (ttx2 - ttx1) * (tty2 - tty1);
    tpb = (int)(0xFFFFFFFFu - bp32[(b * NO + lane) * 2]);
  }

  auto stage = [&](int buf, int row0t) {
    const size_t tile_dw = ((size_t)b * NP + (size_t)row0t) * NC;
    #pragma unroll
    for (int k = 0; k < KC_CH; ++k) {
      size_t idx = tile_dw + (size_t)(k * 256 + lane * 4);
      if (idx > max_dw) idx = max_dw;  // 4-dw aligned clamp (tail tile)
      __builtin_amdgcn_global_load_lds(
          (const __attribute__((address_space(1))) unsigned*)(confu + idx),
          (__attribute__((address_space(3))) unsigned*)(&s_conf[buf][k * 256]),
          16, 0, 0);
    }
  };

  float sumL = 0.0f, sumC = 0.0f;
  int cnt = 0;

  stage(0, block_row0);
  int cur = 0;

  #pragma unroll 1
  for (int t = 0; t < KC_TPB; ++t) {
    asm volatile("s_waitcnt vmcnt(0)" ::: "memory");
    if (t + 1 < KC_TPB) stage(cur ^ 1, block_row0 + (t + 1) * KC_ROWS);

    const int p = block_row0 + t * KC_ROWS + lane;
    const bool valid = (p < NP);
    const int pp = valid ? p : (NP - 1);
    const float4 pr = ((const float4*)priors)[pp];
    const float px1 = pr.x - pr.z * 0.5f, py1 = pr.y - pr.w * 0.5f;
    const float px2 = pr.x + pr.z * 0.5f, py2 = pr.y + pr.w * 0.5f;
    const float areab = (px2 - px1) * (py2 - py1);

    // ---- memory-free match over 50 truths (readlane broadcast) -----------
    float bv = -1.0f;
    int bj = 0, ovj = -1;
    #pragma unroll 2
    for (int j = 0; j < NO; ++j) {
      const float x1 = rl_f(ttx1, j), y1 = rl_f(tty1, j);
      const float x2 = rl_f(ttx2, j), y2 = rl_f(tty2, j);
      const float aa = rl_f(tar, j);
      const int pb = __builtin_amdgcn_readlane(tpb, j);
      const float wx = fmaxf(fminf(x2, px2) - fmaxf(x1, px1), 0.0f);
      const float wy = fmaxf(fminf(y2, py2) - fmaxf(y1, py1), 0.0f);
      const float inter = wx * wy;
      const float iou = __fdividef(inter, aa + areab - inter);
      if (iou > bv) { bv = iou; bj = j; }   // first-max tie-break
      if (pb == p) ovj = j;                  // ascending j -> last wins
    }
    const int j = (ovj >= 0) ? ovj : bj;
    const bool pos = (ovj >= 0) || (bv >= THR);
    const float lab = s_t[j * 5 + 4];        // divergent ds_read (1)
    const int conft = pos ? ((int)lab + 1) : 0;

    // ---- row lse + gather from LDS (thread-local) ------------------------
    const float* rowp = &s_conf[cur][lane * NC];
    float s0 = 0.0f, s1 = 0.0f, s2 = 0.0f, s3 = 0.0f;
    #pragma unroll
    for (int c = 0; c < 80; c += 4) {
      s0 += __expf(rowp[c + 0]);
      s1 += __expf(rowp[c + 1]);
      s2 += __expf(rowp[c + 2]);
      s3 += __expf(rowp[c + 3]);
    }
    const float s = ((s0 + s1) + (s2 + s3)) + __expf(rowp[80]);
    const float gval = rowp[conft];
    const float lca = __logf(s) - gval;

    if (valid) {
      mine[(size_t)b * NP + p] = pos ? 0.0f : fmaxf(lca, 0.0f);
      if (pos) {
        cnt++;
        sumC += lca;
        const float mx1 = s_t[j * 5 + 0], my1 = s_t[j * 5 + 1];
        const float mx2 = s_t[j * 5 + 2], my2 = s_t[j * 5 + 3];
        const float gcx = __fdividef((mx1 + mx2) * 0.5f - pr.x, 0.1f * pr.z);
        const float gcy = __fdividef((my1 + my2) * 0.5f - pr.y, 0.1f * pr.w);
        const float gw = __logf(__fdividef(mx2 - mx1, pr.z)) * 5.0f;
        const float gh = __logf(__fdividef(my2 - my1, pr.w)) * 5.0f;
        const float4 ld = ((const float4*)loc)[(size_t)b * NP + p];
        const float d0 = ld.x - gcx, d1 = ld.y - gcy;
        const float d2 = ld.z - gw, d3 = ld.w - gh;
        float sm = 0.0f;
        #pragma unroll
        for (int q = 0; q < 4; ++q) {
          const float d = (q == 0) ? d0 : (q == 1) ? d1 : (q == 2) ? d2 : d3;
          const float a = fabsf(d);
          sm += (a < 1.0f) ? 0.5f * d * d : a - 0.5f;
        }
        sumL += sm;
      }
    }
    cur ^= 1;
  }

  // ---- single-wave reduce + one atomic per block ---------------------------
  #pragma unroll
  for (int m = 1; m <= 32; m <<= 1) {
    sumL += __shfl_xor(sumL, m, 64);
    sumC += __shfl_xor(sumC, m, 64);
    cnt  += __shfl_xor(cnt, m, 64);
  }
  if (lane == 0) {
    if (sumL != 0.0f) atomicAdd(&accLb[b], sumL);
    if (sumC != 0.0f) atomicAdd(&accCb[b], sumC);
    if (cnt) atomicAdd(&num_pos[b], cnt);
  }
}

// ---------------- Kernel D: exact top-K sum via bitwise radix select -------
__global__ __launch_bounds__(512) void kD(
    const float* __restrict__ mine, const int* __restrict__ num_pos,
    double* __restrict__ acc) {
  const int b = blockIdx.x;
  const int tid = threadIdx.x;
  const float* vb = mine + (size_t)b * NP;

  unsigned vals[48];
  #pragma unroll
  for (int k = 0; k < 48; ++k) {
    const int i = tid + k * 512;
    vals[k] = (i < NP) ? __float_as_uint(vb[i]) : 0u;
  }

  const int K = min(3 * num_pos[b], NP - 1);

  __shared__ int s_w[2][8];
  unsigned prefix = 0u;
  int remaining = K;

  for (int bit = 30; bit >= 0; --bit) {
    const unsigned want = (prefix >> bit) | 1u;
    int cnt = 0;
    #pragma unroll
    for (int k = 0; k < 48; ++k) cnt += ((vals[k] >> bit) == want) ? 1 : 0;
    #pragma unroll
    for (int m = 32; m >= 1; m >>= 1) cnt += __shfl_xor(cnt, m, 64);
    const int buf = bit & 1;
    if ((tid & 63) == 0) s_w[buf][tid >> 6] = cnt;
    __syncthreads();
    int total = 0;
    #pragma unroll
    for (int w = 0; w < 8; ++w) total += s_w[buf][w];
    if (total >= remaining) prefix |= (1u << bit);
    else remaining -= total;
  }

  if (K > 0) {
    const float t = __uint_as_float(prefix);
    double sg = 0.0;
    int cg = 0;
    #pragma unroll
    for (int k = 0; k < 48; ++k) {
      const float f = __uint_as_float(vals[k]);
      if (f > t) { sg += (double)f; cg++; }
    }
    #pragma unroll
    for (int m = 32; m >= 1; m >>= 1) {
      sg += __shfl_xor(sg, m, 64);
      cg += __shfl_xor(cg, m, 64);
    }
    __shared__ double s_sd[8];
    __shared__ int s_sc[8];
    const int wid = tid >> 6;
    if ((tid & 63) == 0) { s_sd[wid] = sg; s_sc[wid] = cg; }
    __syncthreads();
    if (tid == 0) {
      double S = 0.0;
      int C = 0;
      for (int w = 0; w < 8; ++w) { S += s_sd[w]; C += s_sc[w]; }
      S += (double)(K - C) * (double)t;
      atomicAdd(&acc[2], S);
    }
  }
}

// ---------------- Kernel E: finalize ---------------------------------------
__global__ void kE(const double* __restrict__ acc, const float* __restrict__ accLb,
                   const float* __restrict__ accCb, const int* __restrict__ num_pos,
                   float* __restrict__ out) {
  const int lane = threadIdx.x & 63;
  int n = 0;
  float L = 0.0f, C = 0.0f;
  if (lane < NB) { n = num_pos[lane]; L = accLb[lane]; C = accCb[lane]; }
  #pragma unroll
  for (int m = 32; m >= 1; m >>= 1) {
    n += __shfl_xor(n, m, 64);
    L += __shfl_xor(L, m, 64);
    C += __shfl_xor(C, m, 64);
  }
  if (lane == 0 && blockIdx.x == 0) {
    const double Nf = (double)n;
    out[0] = (float)((double)L / Nf);
    out[1] = (float)(((double)C + acc[2]) / Nf);
  }
}

extern "C" void kernel_launch(void* const* d_in, const int* in_sizes, int n_in,
                              void* d_out, int out_size, void* d_ws, size_t ws_size,
                              hipStream_t stream) {
  const float* loc     = (const float*)d_in[0];
  const float* conf    = (const float*)d_in[1];
  const float* priors  = (const float*)d_in[2];
  const float* targets = (const float*)d_in[3];
  float* out = (float*)d_out;

  char* ws = (char*)d_ws;
  double* acc   = (double*)ws;                       // 4 doubles   @ 0    (32 B)
  int* num_pos  = (int*)(ws + 32);                   // 32 ints     @ 32   (128 B)
  float* accLb  = (float*)(ws + 160);                // 32 floats   @ 160  (128 B)
  float* accCb  = (float*)(ws + 288);                // 32 floats   @ 288  (128 B)
  unsigned long long* bp = (unsigned long long*)(ws + 416);  // 1600 u64 (12800 B)
  const size_t hdr = 13216;
  float* mine  = (float*)(ws + hdr);                 // NB*NP floats

  k0<<<1, 256, 0, stream>>>(acc, num_pos, accLb, accCb, bp);

  dim3 gA((NP + KA_CHUNK - 1) / KA_CHUNK, NB);
  kA<<<gA, 256, 0, stream>>>(priors, targets, bp);

  dim3 gC(24, NB);   // 24 blocks x 1024 rows = 24576 >= NP
  kC<<<gC, 64, 0, stream>>>(loc, conf, priors, targets, (const unsigned*)bp,
                            mine, num_pos, accLb, accCb);
  kD<<<NB, 512, 0, stream>>>(mine, num_pos, acc);
  kE<<<1, 64, 0, stream>>>(acc, accLb, accCb, num_pos, out);
}

// Round 8
// 224.688 us; speedup vs baseline: 1.1284x; 1.0066x over previous
//
#include <hip/hip_runtime.h>

#define NB 32
#define NP 24564
#define NO 50
#define NC 81
#define THR 0.5f

__device__ __forceinline__ float rl_f(float v, int j) {
  return __uint_as_float((unsigned)__builtin_amdgcn_readlane((int)__float_as_uint(v), j));
}

// ---------------- Kernel 0: zero-init header -------------------------------
__global__ __launch_bounds__(256) void k0(
    double* __restrict__ acc, int* __restrict__ num_pos,
    float* __restrict__ accLb, float* __restrict__ accCb,
    unsigned long long* __restrict__ bp) {
  const int tid = threadIdx.x;
  if (tid < 4) acc[tid] = 0.0;
  if (tid < NB) { num_pos[tid] = 0; accLb[tid] = 0.0f; accCb[tid] = 0.0f; }
  for (int i = tid; i < NB * NO; i += 256) bp[i] = 0ull;
}

// ---------------- Kernel A: per-truth best prior ---------------------------
#define KA_CHUNK 2048

__global__ __launch_bounds__(256) void kA(
    const float* __restrict__ priors, const float* __restrict__ targets,
    unsigned long long* __restrict__ bp_packed) {
  __shared__ float4 s_pf[KA_CHUNK];
  __shared__ float s_t[NO * 5];
  const int b = blockIdx.y;
  const int tid = threadIdx.x;
  const int base = blockIdx.x * KA_CHUNK;

  for (int i = tid; i < NO * 5; i += 256) s_t[i] = targets[b * NO * 5 + i];

  #pragma unroll
  for (int k = 0; k < KA_CHUNK / 256; ++k) {
    const int p = base + k * 256 + tid;
    float4 pf;
    if (p < NP) {
      const float4 pr = ((const float4*)priors)[p];
      pf = make_float4(pr.x - pr.z * 0.5f, pr.y - pr.w * 0.5f,
                       pr.x + pr.z * 0.5f, pr.y + pr.w * 0.5f);
    } else {
      pf = make_float4(3.0f, 3.0f, 3.0f, 3.0f);  // degenerate: IoU == 0
    }
    s_pf[k * 256 + tid] = pf;
  }
  __syncthreads();

  const int wv = tid >> 6;
  const int lane = tid & 63;
  if (lane < NO) {
    const float tx1 = s_t[lane * 5 + 0], ty1 = s_t[lane * 5 + 1];
    const float tx2 = s_t[lane * 5 + 2], ty2 = s_t[lane * 5 + 3];
    const float area_a = (tx2 - tx1) * (ty2 - ty1);
    const int i0 = wv * (KA_CHUNK / 4);
    unsigned long long best = 0ull;
    #pragma unroll 8
    for (int i = 0; i < KA_CHUNK / 4; ++i) {
      const float4 q = s_pf[i0 + i];
      const float ltx = fmaxf(tx1, q.x), lty = fmaxf(ty1, q.y);
      const float rbx = fminf(tx2, q.z), rby = fminf(ty2, q.w);
      const float wx = fmaxf(rbx - ltx, 0.0f), wy = fmaxf(rby - lty, 0.0f);
      const float inter = wx * wy;
      const float ab = (q.z - q.x) * (q.w - q.y);
      const float iou = __fdividef(inter, area_a + ab - inter);
      const unsigned p = (unsigned)(base + i0 + i);
      const unsigned long long pk =
          (((unsigned long long)__float_as_uint(iou)) << 32) |
          (unsigned long long)(0xFFFFFFFFu - p);
      if (pk > best) best = pk;
    }
    atomicMax(&bp_packed[b * NO + lane], best);
  }
}

// ---------------- Kernel C: lane-per-row, DMA conf, full pipeline ----------
// grid = (24, NB), 64 threads (1 wave). 16 tiles x 64 rows per block.
// Truths in lane-registers (readlane broadcast in match loop).
// Per-lane operands (priors, loc) prefetched one tile ahead, issued BEFORE
// the next tile's global_load_lds stage -> in-order vmcnt retire means the
// compute phase has ZERO memory waits; only the top-of-loop vmcnt(0).
#define KC_ROWS 64
#define KC_TPB 16
#define KC_CH 21                 // ceil(64*81/256) chunks of 1 KB
#define KC_BUFDW (KC_CH * 256)   // 5376 dwords per buffer

__global__ __launch_bounds__(64) void kC(
    const float* __restrict__ loc, const float* __restrict__ conf,
    const float* __restrict__ priors, const float* __restrict__ targets,
    const unsigned* __restrict__ bp32,   // low dwords of bp_packed (LE)
    float* __restrict__ mine, int* __restrict__ num_pos,
    float* __restrict__ accLb, float* __restrict__ accCb) {
  __shared__ float s_conf[2][KC_BUFDW];
  __shared__ float s_t[NO * 5];
  const int lane = threadIdx.x;
  const int b = blockIdx.y;
  const int block_row0 = blockIdx.x * (KC_TPB * KC_ROWS);
  const size_t total_dw = (size_t)NB * NP * NC;
  const size_t max_dw = total_dw - 4;
  const unsigned* confu = (const unsigned*)conf;
  const float* tb = targets + (size_t)b * (NO * 5);

  for (int i = lane; i < NO * 5; i += 64) s_t[i] = tb[i];

  // lane l holds truth l entirely in registers
  float ttx1 = 3.0f, tty1 = 3.0f, ttx2 = 3.0f, tty2 = 3.0f, tar = 0.0f;
  int tpb = -1;
  if (lane < NO) {
    ttx1 = tb[lane * 5 + 0]; tty1 = tb[lane * 5 + 1];
    ttx2 = tb[lane * 5 + 2]; tty2 = tb[lane * 5 + 3];
    tar = (ttx2 - ttx1) * (tty2 - tty1);
    tpb = (int)(0xFFFFFFFFu - bp32[(b * NO + lane) * 2]);
  }

  auto stage = [&](int buf, int row0t) {
    const size_t tile_dw = ((size_t)b * NP + (size_t)row0t) * NC;
    #pragma unroll
    for (int k = 0; k < KC_CH; ++k) {
      size_t idx = tile_dw + (size_t)(k * 256 + lane * 4);
      if (idx > max_dw) idx = max_dw;  // 4-dw aligned clamp (tail tile)
      __builtin_amdgcn_global_load_lds(
          (const __attribute__((address_space(1))) unsigned*)(confu + idx),
          (__attribute__((address_space(3))) unsigned*)(&s_conf[buf][k * 256]),
          16, 0, 0);
    }
  };

  auto clampedp = [&](int t) {
    int p = block_row0 + t * KC_ROWS + lane;
    return (p < NP) ? p : (NP - 1);
  };

  float sumL = 0.0f, sumC = 0.0f;
  int cnt = 0;

  // prologue: operands for tile 0, then DMA for tile 0
  float4 pr = ((const float4*)priors)[clampedp(0)];
  float4 ld = ((const float4*)loc)[(size_t)b * NP + clampedp(0)];
  __builtin_amdgcn_sched_barrier(0);
  stage(0, block_row0);
  int cur = 0;

  #pragma unroll 1
  for (int t = 0; t < KC_TPB; ++t) {
    asm volatile("s_waitcnt vmcnt(0)" ::: "memory");

    // prefetch NEXT tile's per-lane operands BEFORE issuing its DMA
    const int tn = (t + 1 < KC_TPB) ? (t + 1) : t;
    const int ppn = clampedp(tn);
    float4 prn = ((const float4*)priors)[ppn];
    float4 ldn = ((const float4*)loc)[(size_t)b * NP + ppn];
    __builtin_amdgcn_sched_barrier(0);
    if (t + 1 < KC_TPB) stage(cur ^ 1, block_row0 + (t + 1) * KC_ROWS);
    __builtin_amdgcn_sched_barrier(0);

    const int p = block_row0 + t * KC_ROWS + lane;
    const bool valid = (p < NP);
    const float px1 = pr.x - pr.z * 0.5f, py1 = pr.y - pr.w * 0.5f;
    const float px2 = pr.x + pr.z * 0.5f, py2 = pr.y + pr.w * 0.5f;
    const float areab = (px2 - px1) * (py2 - py1);

    // ---- memory-free match over 50 truths (readlane broadcast) -----------
    float bv = -1.0f;
    int bj = 0, ovj = -1;
    #pragma unroll 2
    for (int j = 0; j < NO; ++j) {
      const float x1 = rl_f(ttx1, j), y1 = rl_f(tty1, j);
      const float x2 = rl_f(ttx2, j), y2 = rl_f(tty2, j);
      const float aa = rl_f(tar, j);
      const int pb = __builtin_amdgcn_readlane(tpb, j);
      const float wx = fmaxf(fminf(x2, px2) - fmaxf(x1, px1), 0.0f);
      const float wy = fmaxf(fminf(y2, py2) - fmaxf(y1, py1), 0.0f);
      const float inter = wx * wy;
      const float iou = __fdividef(inter, aa + areab - inter);
      if (iou > bv) { bv = iou; bj = j; }   // first-max tie-break
      if (pb == p) ovj = j;                  // ascending j -> last wins
    }
    const int j = (ovj >= 0) ? ovj : bj;
    const bool pos = (ovj >= 0) || (bv >= THR);
    const float lab = s_t[j * 5 + 4];        // divergent ds_read
    const int conft = pos ? ((int)lab + 1) : 0;

    // ---- row lse + gather from LDS (thread-local) ------------------------
    const float* rowp = &s_conf[cur][lane * NC];
    float s0 = 0.0f, s1 = 0.0f, s2 = 0.0f, s3 = 0.0f;
    #pragma unroll
    for (int c = 0; c < 80; c += 4) {
      s0 += __expf(rowp[c + 0]);
      s1 += __expf(rowp[c + 1]);
      s2 += __expf(rowp[c + 2]);
      s3 += __expf(rowp[c + 3]);
    }
    const float s = ((s0 + s1) + (s2 + s3)) + __expf(rowp[80]);
    const float gval = rowp[conft];
    const float lca = __logf(s) - gval;

    if (valid) {
      mine[(size_t)b * NP + p] = pos ? 0.0f : fmaxf(lca, 0.0f);
      if (pos) {
        cnt++;
        sumC += lca;
        const float mx1 = s_t[j * 5 + 0], my1 = s_t[j * 5 + 1];
        const float mx2 = s_t[j * 5 + 2], my2 = s_t[j * 5 + 3];
        const float gcx = __fdividef((mx1 + mx2) * 0.5f - pr.x, 0.1f * pr.z);
        const float gcy = __fdividef((my1 + my2) * 0.5f - pr.y, 0.1f * pr.w);
        const float gw = __logf(__fdividef(mx2 - mx1, pr.z)) * 5.0f;
        const float gh = __logf(__fdividef(my2 - my1, pr.w)) * 5.0f;
        const float d0 = ld.x - gcx, d1 = ld.y - gcy;
        const float d2 = ld.z - gw, d3 = ld.w - gh;
        float sm = 0.0f;
        #pragma unroll
        for (int q = 0; q < 4; ++q) {
          const float d = (q == 0) ? d0 : (q == 1) ? d1 : (q == 2) ? d2 : d3;
          const float a = fabsf(d);
          sm += (a < 1.0f) ? 0.5f * d * d : a - 0.5f;
        }
        sumL += sm;
      }
    }
    pr = prn;
    ld = ldn;
    cur ^= 1;
  }

  // ---- single-wave reduce + one atomic per block ---------------------------
  #pragma unroll
  for (int m = 1; m <= 32; m <<= 1) {
    sumL += __shfl_xor(sumL, m, 64);
    sumC += __shfl_xor(sumC, m, 64);
    cnt  += __shfl_xor(cnt, m, 64);
  }
  if (lane == 0) {
    if (sumL != 0.0f) atomicAdd(&accLb[b], sumL);
    if (sumC != 0.0f) atomicAdd(&accCb[b], sumC);
    if (cnt) atomicAdd(&num_pos[b], cnt);
  }
}

// ---------------- Kernel D: exact top-K sum via bitwise radix select -------
__global__ __launch_bounds__(512) void kD(
    const float* __restrict__ mine, const int* __restrict__ num_pos,
    double* __restrict__ acc) {
  const int b = blockIdx.x;
  const int tid = threadIdx.x;
  const float* vb = mine + (size_t)b * NP;

  unsigned vals[48];
  #pragma unroll
  for (int k = 0; k < 48; ++k) {
    const int i = tid + k * 512;
    vals[k] = (i < NP) ? __float_as_uint(vb[i]) : 0u;
  }

  const int K = min(3 * num_pos[b], NP - 1);

  __shared__ int s_w[2][8];
  unsigned prefix = 0u;
  int remaining = K;

  for (int bit = 30; bit >= 0; --bit) {
    const unsigned want = (prefix >> bit) | 1u;
    int cnt = 0;
    #pragma unroll
    for (int k = 0; k < 48; ++k) cnt += ((vals[k] >> bit) == want) ? 1 : 0;
    #pragma unroll
    for (int m = 32; m >= 1; m >>= 1) cnt += __shfl_xor(cnt, m, 64);
    const int buf = bit & 1;
    if ((tid & 63) == 0) s_w[buf][tid >> 6] = cnt;
    __syncthreads();
    int total = 0;
    #pragma unroll
    for (int w = 0; w < 8; ++w) total += s_w[buf][w];
    if (total >= remaining) prefix |= (1u << bit);
    else remaining -= total;
  }

  if (K > 0) {
    const float t = __uint_as_float(prefix);
    double sg = 0.0;
    int cg = 0;
    #pragma unroll
    for (int k = 0; k < 48; ++k) {
      const float f = __uint_as_float(vals[k]);
      if (f > t) { sg += (double)f; cg++; }
    }
    #pragma unroll
    for (int m = 32; m >= 1; m >>= 1) {
      sg += __shfl_xor(sg, m, 64);
      cg += __shfl_xor(cg, m, 64);
    }
    __shared__ double s_sd[8];
    __shared__ int s_sc[8];
    const int wid = tid >> 6;
    if ((tid & 63) == 0) { s_sd[wid] = sg; s_sc[wid] = cg; }
    __syncthreads();
    if (tid == 0) {
      double S = 0.0;
      int C = 0;
      for (int w = 0; w < 8; ++w) { S += s_sd[w]; C += s_sc[w]; }
      S += (double)(K - C) * (double)t;
      atomicAdd(&acc[2], S);
    }
  }
}

// ---------------- Kernel E: finalize ---------------------------------------
__global__ void kE(const double* __restrict__ acc, const float* __restrict__ accLb,
                   const float* __restrict__ accCb, const int* __restrict__ num_pos,
                   float* __restrict__ out) {
  const int lane = threadIdx.x & 63;
  int n = 0;
  float L = 0.0f, C = 0.0f;
  if (lane < NB) { n = num_pos[lane]; L = accLb[lane]; C = accCb[lane]; }
  #pragma unroll
  for (int m = 32; m >= 1; m >>= 1) {
    n += __shfl_xor(n, m, 64);
    L += __shfl_xor(L, m, 64);
    C += __shfl_xor(C, m, 64);
  }
  if (lane == 0 && blockIdx.x == 0) {
    const double Nf = (double)n;
    out[0] = (float)((double)L / Nf);
    out[1] = (float)(((double)C + acc[2]) / Nf);
  }
}

extern "C" void kernel_launch(void* const* d_in, const int* in_sizes, int n_in,
                              void* d_out, int out_size, void* d_ws, size_t ws_size,
                              hipStream_t stream) {
  const float* loc     = (const float*)d_in[0];
  const float* conf    = (const float*)d_in[1];
  const float* priors  = (const float*)d_in[2];
  const float* targets = (const float*)d_in[3];
  float* out = (float*)d_out;

  char* ws = (char*)d_ws;
  double* acc   = (double*)ws;                       // 4 doubles   @ 0    (32 B)
  int* num_pos  = (int*)(ws + 32);                   // 32 ints     @ 32   (128 B)
  float* accLb  = (float*)(ws + 160);                // 32 floats   @ 160  (128 B)
  float* accCb  = (float*)(ws + 288);                // 32 floats   @ 288  (128 B)
  unsigned long long* bp = (unsigned long long*)(ws + 416);  // 1600 u64 (12800 B)
  const size_t hdr = 13216;
  float* mine  = (float*)(ws + hdr);                 // NB*NP floats

  k0<<<1, 256, 0, stream>>>(acc, num_pos, accLb, accCb, bp);

  dim3 gA((NP + KA_CHUNK - 1) / KA_CHUNK, NB);
  kA<<<gA, 256, 0, stream>>>(priors, targets, bp);

  dim3 gC(24, NB);   // 24 blocks x 1024 rows = 24576 >= NP
  kC<<<gC, 64, 0, stream>>>(loc, conf, priors, targets, (const unsigned*)bp,
                            mine, num_pos, accLb, accCb);
  kD<<<NB, 512, 0, stream>>>(mine, num_pos, acc);
  kE<<<1, 64, 0, stream>>>(acc, accLb, accCb, num_pos, out);
}

// Round 9
// 159.216 us; speedup vs baseline: 1.5924x; 1.4112x over previous
//
#include <hip/hip_runtime.h>

#define NB 32
#define NP 24564
#define NO 50
#define NC 81
#define THR 0.5f

__device__ __forceinline__ float rl_f(float v, int j) {
  return __uint_as_float((unsigned)__builtin_amdgcn_readlane((int)__float_as_uint(v), j));
}
__device__ __forceinline__ float bp_f(float v, int j4) {
  return __uint_as_float((unsigned)__builtin_amdgcn_ds_bpermute(j4, (int)__float_as_uint(v)));
}

// ws header: acc dbl[4]@0 | num_pos i32[32]@32 | accLb f[32]@160 | accCb f[32]@288
//            done i32@416 | bp u64[1600]@424 | hdr=13224 | mine f[NB*NP]@hdr

// ---------------- Kernel 0: zero-init header -------------------------------
__global__ __launch_bounds__(256) void k0(
    double* __restrict__ acc, int* __restrict__ num_pos,
    float* __restrict__ accLb, float* __restrict__ accCb,
    int* __restrict__ done, unsigned long long* __restrict__ bp) {
  const int tid = threadIdx.x;
  if (tid < 4) acc[tid] = 0.0;
  if (tid < NB) { num_pos[tid] = 0; accLb[tid] = 0.0f; accCb[tid] = 0.0f; }
  if (tid == 4) *done = 0;
  for (int i = tid; i < NB * NO; i += 256) bp[i] = 0ull;
}

// ---------------- Kernel A: per-truth best prior ---------------------------
#define KA_CHUNK 1024

__global__ __launch_bounds__(256) void kA(
    const float* __restrict__ priors, const float* __restrict__ targets,
    unsigned long long* __restrict__ bp_packed) {
  __shared__ float4 s_pf[KA_CHUNK];
  __shared__ float s_t[NO * 5];
  const int b = blockIdx.y;
  const int tid = threadIdx.x;
  const int base = blockIdx.x * KA_CHUNK;

  for (int i = tid; i < NO * 5; i += 256) s_t[i] = targets[b * NO * 5 + i];

  #pragma unroll
  for (int k = 0; k < KA_CHUNK / 256; ++k) {
    const int p = base + k * 256 + tid;
    float4 pf;
    if (p < NP) {
      const float4 pr = ((const float4*)priors)[p];
      pf = make_float4(pr.x - pr.z * 0.5f, pr.y - pr.w * 0.5f,
                       pr.x + pr.z * 0.5f, pr.y + pr.w * 0.5f);
    } else {
      pf = make_float4(3.0f, 3.0f, 3.0f, 3.0f);  // degenerate: IoU == 0
    }
    s_pf[k * 256 + tid] = pf;
  }
  __syncthreads();

  const int wv = tid >> 6;
  const int lane = tid & 63;
  if (lane < NO) {
    const float tx1 = s_t[lane * 5 + 0], ty1 = s_t[lane * 5 + 1];
    const float tx2 = s_t[lane * 5 + 2], ty2 = s_t[lane * 5 + 3];
    const float area_a = (tx2 - tx1) * (ty2 - ty1);
    const int i0 = wv * (KA_CHUNK / 4);
    unsigned long long best = 0ull;
    #pragma unroll 8
    for (int i = 0; i < KA_CHUNK / 4; ++i) {
      const float4 q = s_pf[i0 + i];
      const float ltx = fmaxf(tx1, q.x), lty = fmaxf(ty1, q.y);
      const float rbx = fminf(tx2, q.z), rby = fminf(ty2, q.w);
      const float wx = fmaxf(rbx - ltx, 0.0f), wy = fmaxf(rby - lty, 0.0f);
      const float inter = wx * wy;
      const float ab = (q.z - q.x) * (q.w - q.y);
      const float iou = __fdividef(inter, area_a + ab - inter);
      const unsigned p = (unsigned)(base + i0 + i);
      const unsigned long long pk =
          (((unsigned long long)__float_as_uint(iou)) << 32) |
          (unsigned long long)(0xFFFFFFFFu - p);
      if (pk > best) best = pk;
    }
    atomicMax(&bp_packed[b * NO + lane], best);
  }
}

// ---------------- Kernel MS: match + lse, high occupancy, no conf staging --
// grid = (96, NB), 256 threads. Each wave owns 64 rows.
// Phase 1 (lane-per-row): readlane match, ballot override, bpermute truth,
//   direct global gather of conf[row*81+conft], smooth-L1.
// Phase 2 (16-lane groups, 16 passes): coalesced row lse, shuffle reduce,
//   group sums parked in LDS, owner lane reads s_s[tid].
__global__ __launch_bounds__(256) void kMS(
    const float* __restrict__ loc, const float* __restrict__ conf,
    const float* __restrict__ priors, const float* __restrict__ targets,
    const unsigned* __restrict__ bp32,
    float* __restrict__ mine, int* __restrict__ num_pos,
    float* __restrict__ accLb, float* __restrict__ accCb) {
  __shared__ float s_s[256];
  __shared__ float sLw[4], sCw[4];
  __shared__ int sNw[4];
  const int tid = threadIdx.x;
  const int lane = tid & 63;
  const int b = blockIdx.y;
  const int rowbase = blockIdx.x * 256 + (tid & 192);  // wave's first row
  const int p = rowbase + lane;
  const bool valid = (p < NP);
  const int pc = valid ? p : NP - 1;
  const size_t grow = (size_t)b * NP + pc;
  const float* tb = targets + (size_t)b * (NO * 5);

  // lane l (<50) holds truth l in registers
  float ttx1 = 3.f, tty1 = 3.f, ttx2 = 3.f, tty2 = 3.f, tar = 0.f, tlab = 0.f;
  int tpb = -1;
  if (lane < NO) {
    ttx1 = tb[lane * 5 + 0]; tty1 = tb[lane * 5 + 1];
    ttx2 = tb[lane * 5 + 2]; tty2 = tb[lane * 5 + 3];
    tlab = tb[lane * 5 + 4];
    tar = (ttx2 - ttx1) * (tty2 - tty1);
    tpb = (int)(0xFFFFFFFFu - bp32[(b * NO + lane) * 2]);
  }

  const float4 pr = ((const float4*)priors)[pc];
  const float4 ldv = ((const float4*)loc)[grow];
  const float px1 = pr.x - pr.z * 0.5f, py1 = pr.y - pr.w * 0.5f;
  const float px2 = pr.x + pr.z * 0.5f, py2 = pr.y + pr.w * 0.5f;
  const float areab = (px2 - px1) * (py2 - py1);

  // ---- match: memory-free 50-truth loop --------------------------------
  float bv = -1.0f;
  int bj = 0;
  #pragma unroll 2
  for (int j = 0; j < NO; ++j) {
    const float x1 = rl_f(ttx1, j), y1 = rl_f(tty1, j);
    const float x2 = rl_f(ttx2, j), y2 = rl_f(tty2, j);
    const float aa = rl_f(tar, j);
    const float wx = fmaxf(fminf(x2, px2) - fmaxf(x1, px1), 0.0f);
    const float wy = fmaxf(fminf(y2, py2) - fmaxf(y1, py1), 0.0f);
    const float inter = wx * wy;
    const float iou = __fdividef(inter, aa + areab - inter);
    if (iou > bv) { bv = iou; bj = j; }   // first-max tie-break
  }

  // ---- forced-match override via ballot scan (rare) --------------------
  int ovj = -1;
  unsigned long long M = __ballot((lane < NO) && ((unsigned)(tpb - rowbase) < 64u));
  while (M) {
    const int l = __ffsll((long long)M) - 1;
    M &= M - 1;
    const int r = __builtin_amdgcn_readlane(tpb, l) - rowbase;
    if (lane == r) ovj = l;              // ascending l -> last j wins
  }
  const int jm = (ovj >= 0) ? ovj : bj;
  const bool pos = valid && ((ovj >= 0) || (bv >= THR));
  const int j4 = jm << 2;
  const float lab = bp_f(tlab, j4);      // unconditional: all lanes active
  const float mx1 = bp_f(ttx1, j4), my1 = bp_f(tty1, j4);
  const float mx2 = bp_f(ttx2, j4), my2 = bp_f(tty2, j4);
  const int conft = pos ? ((int)lab + 1) : 0;

  // direct global gather (row just about to be streamed; L2-friendly)
  const float gval = conf[grow * NC + conft];

  // ---- smooth-L1 (positives only) --------------------------------------
  float sl1 = 0.0f;
  if (pos) {
    const float gcx = __fdividef((mx1 + mx2) * 0.5f - pr.x, 0.1f * pr.z);
    const float gcy = __fdividef((my1 + my2) * 0.5f - pr.y, 0.1f * pr.w);
    const float gw = __logf(__fdividef(mx2 - mx1, pr.z)) * 5.0f;
    const float gh = __logf(__fdividef(my2 - my1, pr.w)) * 5.0f;
    const float d0 = ldv.x - gcx, d1 = ldv.y - gcy;
    const float d2 = ldv.z - gw, d3 = ldv.w - gh;
    #pragma unroll
    for (int q = 0; q < 4; ++q) {
      const float d = (q == 0) ? d0 : (q == 1) ? d1 : (q == 2) ? d2 : d3;
      const float a = fabsf(d);
      sl1 += (a < 1.0f) ? 0.5f * d * d : a - 0.5f;
    }
  }

  // ---- lse: 16-lane groups, 16 passes, coalesced loads ------------------
  const int l16 = lane & 15;
  const int g4 = (lane >> 4) & 3;
  #pragma unroll 2
  for (int ph = 0; ph < 16; ++ph) {
    const int ro = ph * 4 + g4;          // row offset within wave tile
    const int rr = rowbase + ro;
    const int rc = (rr < NP) ? rr : NP - 1;
    const float* rowp = conf + ((size_t)b * NP + rc) * NC;
    float s0 = __expf(rowp[l16]);
    float s1 = __expf(rowp[l16 + 16]);
    s0 += __expf(rowp[l16 + 32]);
    s1 += __expf(rowp[l16 + 48]);
    s0 += __expf(rowp[l16 + 64]);
    if (l16 == 0) s1 += __expf(rowp[80]);
    float s = s0 + s1;
    s += __shfl_xor(s, 1, 64);
    s += __shfl_xor(s, 2, 64);
    s += __shfl_xor(s, 4, 64);
    s += __shfl_xor(s, 8, 64);
    if (l16 == 0) s_s[(tid & 192) + ro] = s;
  }
  const float myS = s_s[tid];            // wave-local; lgkmcnt ordered

  const float lca = __logf(myS) - gval;
  float sumL = 0.0f, sumC = 0.0f;
  int cnt = 0;
  if (valid) {
    mine[grow] = pos ? 0.0f : fmaxf(lca, 0.0f);
    if (pos) { cnt = 1; sumC = lca; sumL = sl1; }
  }

  // ---- wave + block reduce, one atomic set per block --------------------
  #pragma unroll
  for (int m = 1; m <= 32; m <<= 1) {
    sumL += __shfl_xor(sumL, m, 64);
    sumC += __shfl_xor(sumC, m, 64);
    cnt  += __shfl_xor(cnt, m, 64);
  }
  const int w = tid >> 6;
  if (lane == 0) { sLw[w] = sumL; sCw[w] = sumC; sNw[w] = cnt; }
  __syncthreads();
  if (tid == 0) {
    const float L = sLw[0] + sLw[1] + sLw[2] + sLw[3];
    const float C = sCw[0] + sCw[1] + sCw[2] + sCw[3];
    const int n = sNw[0] + sNw[1] + sNw[2] + sNw[3];
    if (L != 0.0f) atomicAdd(&accLb[b], L);
    if (C != 0.0f) atomicAdd(&accCb[b], C);
    if (n) atomicAdd(&num_pos[b], n);
  }
}

// ---------------- Kernel D: top-K radix select + fused finalize ------------
__global__ __launch_bounds__(512) void kD(
    const float* __restrict__ mine, const int* __restrict__ num_pos,
    double* __restrict__ acc, int* __restrict__ done,
    const float* __restrict__ accLb, const float* __restrict__ accCb,
    float* __restrict__ out) {
  const int b = blockIdx.x;
  const int tid = threadIdx.x;
  const float* vb = mine + (size_t)b * NP;

  unsigned vals[48];
  #pragma unroll
  for (int k = 0; k < 48; ++k) {
    const int i = tid + k * 512;
    vals[k] = (i < NP) ? __float_as_uint(vb[i]) : 0u;
  }

  const int K = min(3 * num_pos[b], NP - 1);

  __shared__ int s_w[2][8];
  unsigned prefix = 0u;
  int remaining = K;

  for (int bit = 30; bit >= 0; --bit) {
    const unsigned want = (prefix >> bit) | 1u;
    int cnt = 0;
    #pragma unroll
    for (int k = 0; k < 48; ++k) cnt += ((vals[k] >> bit) == want) ? 1 : 0;
    #pragma unroll
    for (int m = 32; m >= 1; m >>= 1) cnt += __shfl_xor(cnt, m, 64);
    const int buf = bit & 1;
    if ((tid & 63) == 0) s_w[buf][tid >> 6] = cnt;
    __syncthreads();
    int total = 0;
    #pragma unroll
    for (int w = 0; w < 8; ++w) total += s_w[buf][w];
    if (total >= remaining) prefix |= (1u << bit);
    else remaining -= total;
  }

  if (K > 0) {
    const float t = __uint_as_float(prefix);
    double sg = 0.0;
    int cg = 0;
    #pragma unroll
    for (int k = 0; k < 48; ++k) {
      const float f = __uint_as_float(vals[k]);
      if (f > t) { sg += (double)f; cg++; }
    }
    #pragma unroll
    for (int m = 32; m >= 1; m >>= 1) {
      sg += __shfl_xor(sg, m, 64);
      cg += __shfl_xor(cg, m, 64);
    }
    __shared__ double s_sd[8];
    __shared__ int s_sc[8];
    const int wid = tid >> 6;
    if ((tid & 63) == 0) { s_sd[wid] = sg; s_sc[wid] = cg; }
    __syncthreads();
    if (tid == 0) {
      double S = 0.0;
      int C = 0;
      for (int w = 0; w < 8; ++w) { S += s_sd[w]; C += s_sc[w]; }
      S += (double)(K - C) * (double)t;
      atomicAdd(&acc[2], S);
    }
  }

  // ---- last block finalizes (replaces kE) -------------------------------
  __shared__ int s_last;
  __syncthreads();
  if (tid == 0) {
    __threadfence();
    s_last = (atomicAdd(done, 1) == NB - 1) ? 1 : 0;
  }
  __syncthreads();
  if (s_last && tid < 64) {
    int n = 0;
    float L = 0.0f, C = 0.0f;
    if (tid < NB) { n = num_pos[tid]; L = accLb[tid]; C = accCb[tid]; }
    #pragma unroll
    for (int m = 32; m >= 1; m >>= 1) {
      n += __shfl_xor(n, m, 64);
      L += __shfl_xor(L, m, 64);
      C += __shfl_xor(C, m, 64);
    }
    if (tid == 0) {
      const double S = atomicAdd(&acc[2], 0.0);  // coherent read of all adds
      const double Nf = (double)n;
      out[0] = (float)((double)L / Nf);
      out[1] = (float)(((double)C + S) / Nf);
    }
  }
}

extern "C" void kernel_launch(void* const* d_in, const int* in_sizes, int n_in,
                              void* d_out, int out_size, void* d_ws, size_t ws_size,
                              hipStream_t stream) {
  const float* loc     = (const float*)d_in[0];
  const float* conf    = (const float*)d_in[1];
  const float* priors  = (const float*)d_in[2];
  const float* targets = (const float*)d_in[3];
  float* out = (float*)d_out;

  char* ws = (char*)d_ws;
  double* acc   = (double*)ws;
  int* num_pos  = (int*)(ws + 32);
  float* accLb  = (float*)(ws + 160);
  float* accCb  = (float*)(ws + 288);
  int* done     = (int*)(ws + 416);
  unsigned long long* bp = (unsigned long long*)(ws + 424);
  const size_t hdr = 13224;
  float* mine  = (float*)(ws + hdr);

  k0<<<1, 256, 0, stream>>>(acc, num_pos, accLb, accCb, done, bp);

  dim3 gA((NP + KA_CHUNK - 1) / KA_CHUNK, NB);
  kA<<<gA, 256, 0, stream>>>(priors, targets, bp);

  dim3 gM((NP + 255) / 256, NB);
  kMS<<<gM, 256, 0, stream>>>(loc, conf, priors, targets, (const unsigned*)bp,
                              mine, num_pos, accLb, accCb);

  kD<<<NB, 512, 0, stream>>>(mine, num_pos, acc, done, accLb, accCb, out);
}

// Round 10
// 154.012 us; speedup vs baseline: 1.6462x; 1.0338x over previous
//
#include <hip/hip_runtime.h>

#define NB 32
#define NP 24564
#define NO 50
#define NC 81
#define THR 0.5f
#define KA_CHUNK 1024
#define NCH 24   // ceil(NP / KA_CHUNK)

__device__ __forceinline__ float rl_f(float v, int j) {
  return __uint_as_float((unsigned)__builtin_amdgcn_readlane((int)__float_as_uint(v), j));
}
__device__ __forceinline__ float bp_f(float v, int j4) {
  return __uint_as_float((unsigned)__builtin_amdgcn_ds_bpermute(j4, (int)__float_as_uint(v)));
}

// ws: acc dbl[4]@0 | num_pos i32[32]@32 | accLb f[32]@160 | accCb f[32]@288
//     done i32@416 | bpc u64[NB*NO*NCH]@424 | hdr=424+307200 | mine f[NB*NP]

// ---------------- Kernel A: per-truth per-chunk best prior + init ----------
// grid (NCH, NB), 256 thr. No atomics: each (b,j,chunk) slot written once.
// Block (0,0) also zero-inits the accumulators (stream-ordered before kMS).
__global__ __launch_bounds__(256) void kA(
    const float* __restrict__ priors, const float* __restrict__ targets,
    unsigned long long* __restrict__ bpc,
    double* __restrict__ acc, int* __restrict__ num_pos,
    float* __restrict__ accLb, float* __restrict__ accCb,
    int* __restrict__ done) {
  __shared__ float4 s_pf[KA_CHUNK];
  __shared__ float s_t[NO * 5];
  __shared__ unsigned long long s_bp[256];
  const int b = blockIdx.y;
  const int tid = threadIdx.x;
  const int base = blockIdx.x * KA_CHUNK;

  if (blockIdx.x == 0 && b == 0) {
    if (tid < 4) acc[tid] = 0.0;
    else if (tid >= 32 && tid < 64) num_pos[tid - 32] = 0;
    else if (tid >= 64 && tid < 96) accLb[tid - 64] = 0.0f;
    else if (tid >= 96 && tid < 128) accCb[tid - 96] = 0.0f;
    else if (tid == 128) *done = 0;
  }

  for (int i = tid; i < NO * 5; i += 256) s_t[i] = targets[b * NO * 5 + i];

  #pragma unroll
  for (int k = 0; k < KA_CHUNK / 256; ++k) {
    const int p = base + k * 256 + tid;
    float4 pf;
    if (p < NP) {
      const float4 pr = ((const float4*)priors)[p];
      pf = make_float4(pr.x - pr.z * 0.5f, pr.y - pr.w * 0.5f,
                       pr.x + pr.z * 0.5f, pr.y + pr.w * 0.5f);
    } else {
      pf = make_float4(3.0f, 3.0f, 3.0f, 3.0f);  // degenerate: IoU == 0, loses ties
    }
    s_pf[k * 256 + tid] = pf;
  }
  __syncthreads();

  const int wv = tid >> 6;
  const int lane = tid & 63;
  unsigned long long best = 0ull;
  if (lane < NO) {
    const float tx1 = s_t[lane * 5 + 0], ty1 = s_t[lane * 5 + 1];
    const float tx2 = s_t[lane * 5 + 2], ty2 = s_t[lane * 5 + 3];
    const float area_a = (tx2 - tx1) * (ty2 - ty1);
    const int i0 = wv * 256;
    #pragma unroll 8
    for (int i = 0; i < 256; ++i) {
      const float4 q = s_pf[i0 + i];
      const float wx = fmaxf(fminf(q.z, tx2) - fmaxf(q.x, tx1), 0.0f);
      const float wy = fmaxf(fminf(q.w, ty2) - fmaxf(q.y, ty1), 0.0f);
      const float inter = wx * wy;
      const float ab = (q.z - q.x) * (q.w - q.y);
      const float iou = __fdividef(inter, area_a + ab - inter);
      const unsigned p = (unsigned)(base + i0 + i);
      const unsigned long long pk =
          (((unsigned long long)__float_as_uint(iou)) << 32) |
          (unsigned long long)(0xFFFFFFFFu - p);
      if (pk > best) best = pk;
    }
  }
  s_bp[tid] = best;
  __syncthreads();
  if (tid < NO) {
    unsigned long long m = s_bp[tid];
    unsigned long long v = s_bp[64 + tid];  if (v > m) m = v;
    v = s_bp[128 + tid];                    if (v > m) m = v;
    v = s_bp[192 + tid];                    if (v > m) m = v;
    bpc[(size_t)(b * NO + tid) * NCH + blockIdx.x] = m;
  }
}

// ---------------- Kernel MS: match + lse (aligned float4) + smooth-L1 ------
// grid (96, NB), 256 thr; wave owns 64 rows. Phase 0: chunk-reduce bpc->LDS.
// Match: lane-per-row readlane loop; override via ballot; bpermute coords.
// lse: 16-lane groups; col start c0=(4-g4)&3 makes float4 loads 16B-aligned.
__global__ __launch_bounds__(256) void kMS(
    const float* __restrict__ loc, const float* __restrict__ conf,
    const float* __restrict__ priors, const float* __restrict__ targets,
    const unsigned long long* __restrict__ bpc,
    float* __restrict__ mine, int* __restrict__ num_pos,
    float* __restrict__ accLb, float* __restrict__ accCb) {
  __shared__ float s_s[256];
  __shared__ int s_tpb[NO];
  __shared__ float sLw[4], sCw[4];
  __shared__ int sNw[4];
  const int tid = threadIdx.x;
  const int lane = tid & 63;
  const int b = blockIdx.y;
  const int rowbase = blockIdx.x * 256 + (tid & 192);
  const int p = rowbase + lane;
  const bool valid = (p < NP);
  const int pc = valid ? p : NP - 1;
  const size_t grow = (size_t)b * NP + pc;
  const float* tb = targets + (size_t)b * (NO * 5);

  // phase 0: reduce 24 chunk slots per truth -> global-best prior per truth
  if (tid < NO) {
    const unsigned long long* sl = bpc + (size_t)(b * NO + tid) * NCH;
    unsigned long long m = 0ull;
    #pragma unroll
    for (int c = 0; c < NCH; ++c) {
      const unsigned long long v = sl[c];
      if (v > m) m = v;
    }
    s_tpb[tid] = (int)(0xFFFFFFFFu - (unsigned)(m & 0xFFFFFFFFull));
  }

  // lane l (<50) holds truth l in registers
  float ttx1 = 3.f, tty1 = 3.f, ttx2 = 3.f, tty2 = 3.f, tar = 0.f, tlab = 0.f;
  if (lane < NO) {
    ttx1 = tb[lane * 5 + 0]; tty1 = tb[lane * 5 + 1];
    ttx2 = tb[lane * 5 + 2]; tty2 = tb[lane * 5 + 3];
    tlab = tb[lane * 5 + 4];
    tar = (ttx2 - ttx1) * (tty2 - tty1);
  }
  const float4 pr = ((const float4*)priors)[pc];
  const float4 ldv = ((const float4*)loc)[grow];
  const float px1 = pr.x - pr.z * 0.5f, py1 = pr.y - pr.w * 0.5f;
  const float px2 = pr.x + pr.z * 0.5f, py2 = pr.y + pr.w * 0.5f;
  const float areab = (px2 - px1) * (py2 - py1);
  __syncthreads();
  const int tpb = (lane < NO) ? s_tpb[lane] : -1;

  // ---- match: memory-free 50-truth loop --------------------------------
  float bv = -1.0f;
  int bj = 0;
  #pragma unroll 2
  for (int j = 0; j < NO; ++j) {
    const float x1 = rl_f(ttx1, j), y1 = rl_f(tty1, j);
    const float x2 = rl_f(ttx2, j), y2 = rl_f(tty2, j);
    const float aa = rl_f(tar, j);
    const float wx = fmaxf(fminf(x2, px2) - fmaxf(x1, px1), 0.0f);
    const float wy = fmaxf(fminf(y2, py2) - fmaxf(y1, py1), 0.0f);
    const float inter = wx * wy;
    const float iou = __fdividef(inter, aa + areab - inter);
    if (iou > bv) { bv = iou; bj = j; }   // first-max tie-break
  }

  // ---- forced-match override via ballot scan (rare) --------------------
  int ovj = -1;
  unsigned long long M = __ballot((lane < NO) && ((unsigned)(tpb - rowbase) < 64u));
  while (M) {
    const int l = __ffsll((long long)M) - 1;
    M &= M - 1;
    const int r = __builtin_amdgcn_readlane(tpb, l) - rowbase;
    if (lane == r) ovj = l;              // ascending l -> last j wins
  }
  const int jm = (ovj >= 0) ? ovj : bj;
  const bool pos = valid && ((ovj >= 0) || (bv >= THR));
  const int j4 = jm << 2;
  const float lab = bp_f(tlab, j4);      // unconditional: all lanes active
  const float mx1 = bp_f(ttx1, j4), my1 = bp_f(tty1, j4);
  const float mx2 = bp_f(ttx2, j4), my2 = bp_f(tty2, j4);
  const int conft = pos ? ((int)lab + 1) : 0;

  // ---- smooth-L1 (positives only) --------------------------------------
  float sl1 = 0.0f;
  if (pos) {
    const float gcx = __fdividef((mx1 + mx2) * 0.5f - pr.x, 0.1f * pr.z);
    const float gcy = __fdividef((my1 + my2) * 0.5f - pr.y, 0.1f * pr.w);
    const float gw = __logf(__fdividef(mx2 - mx1, pr.z)) * 5.0f;
    const float gh = __logf(__fdividef(my2 - my1, pr.w)) * 5.0f;
    const float d0 = ldv.x - gcx, d1 = ldv.y - gcy;
    const float d2 = ldv.z - gw, d3 = ldv.w - gh;
    #pragma unroll
    for (int q = 0; q < 4; ++q) {
      const float d = (q == 0) ? d0 : (q == 1) ? d1 : (q == 2) ? d2 : d3;
      const float a = fabsf(d);
      sl1 += (a < 1.0f) ? 0.5f * d * d : a - 0.5f;
    }
  }

  // ---- lse: 16-lane groups, aligned float4 + 17-col tail ----------------
  const int l16 = lane & 15;
  const int g4 = (lane >> 4) & 3;
  const int c0 = (4 - g4) & 3;           // makes float4 base 16B-aligned
  #pragma unroll 2
  for (int ph = 0; ph < 16; ++ph) {
    const int ro = ph * 4 + g4;
    const int rr = rowbase + ro;
    const int rc = (rr < NP) ? rr : NP - 1;
    const float* rowp = conf + ((size_t)b * NP + rc) * NC;
    const float4 v = *(const float4*)(rowp + c0 + 4 * l16);
    float s = __expf(v.x) + __expf(v.y) + __expf(v.z) + __expf(v.w);
    const int tc = (l16 < c0) ? l16 : (c0 + 64 + (l16 - c0));
    s += __expf(rowp[tc]);
    if (l16 == 0) s += __expf(rowp[80]);
    s += __shfl_xor(s, 1, 64);
    s += __shfl_xor(s, 2, 64);
    s += __shfl_xor(s, 4, 64);
    s += __shfl_xor(s, 8, 64);
    if (l16 == 0) s_s[(tid & 192) + ro] = s;
  }
  const float myS = s_s[tid];            // wave-local; lgkmcnt ordered

  // gather AFTER lse: this wave's rows are cache-hot now
  const float gval = conf[grow * NC + conft];
  const float lca = __logf(myS) - gval;

  float sumL = 0.0f, sumC = 0.0f;
  int cnt = 0;
  if (valid) {
    mine[grow] = pos ? 0.0f : fmaxf(lca, 0.0f);
    if (pos) { cnt = 1; sumC = lca; sumL = sl1; }
  }

  // ---- wave + block reduce, one atomic set per block --------------------
  #pragma unroll
  for (int m = 1; m <= 32; m <<= 1) {
    sumL += __shfl_xor(sumL, m, 64);
    sumC += __shfl_xor(sumC, m, 64);
    cnt  += __shfl_xor(cnt, m, 64);
  }
  const int w = tid >> 6;
  if (lane == 0) { sLw[w] = sumL; sCw[w] = sumC; sNw[w] = cnt; }
  __syncthreads();
  if (tid == 0) {
    const float L = sLw[0] + sLw[1] + sLw[2] + sLw[3];
    const float C = sCw[0] + sCw[1] + sCw[2] + sCw[3];
    const int n = sNw[0] + sNw[1] + sNw[2] + sNw[3];
    if (L != 0.0f) atomicAdd(&accLb[b], L);
    if (C != 0.0f) atomicAdd(&accCb[b], C);
    if (n) atomicAdd(&num_pos[b], n);
  }
}

// ---------------- Kernel D: top-K radix select + fused finalize ------------
__global__ __launch_bounds__(512) void kD(
    const float* __restrict__ mine, const int* __restrict__ num_pos,
    double* __restrict__ acc, int* __restrict__ done,
    const float* __restrict__ accLb, const float* __restrict__ accCb,
    float* __restrict__ out) {
  const int b = blockIdx.x;
  const int tid = threadIdx.x;
  const float* vb = mine + (size_t)b * NP;

  unsigned vals[48];
  #pragma unroll
  for (int k = 0; k < 48; ++k) {
    const int i = tid + k * 512;
    vals[k] = (i < NP) ? __float_as_uint(vb[i]) : 0u;
  }

  const int K = min(3 * num_pos[b], NP - 1);

  __shared__ int s_w[2][8];
  unsigned prefix = 0u;
  int remaining = K;

  for (int bit = 30; bit >= 0; --bit) {
    const unsigned want = (prefix >> bit) | 1u;
    int cnt = 0;
    #pragma unroll
    for (int k = 0; k < 48; ++k) cnt += ((vals[k] >> bit) == want) ? 1 : 0;
    #pragma unroll
    for (int m = 32; m >= 1; m >>= 1) cnt += __shfl_xor(cnt, m, 64);
    const int buf = bit & 1;
    if ((tid & 63) == 0) s_w[buf][tid >> 6] = cnt;
    __syncthreads();
    int total = 0;
    #pragma unroll
    for (int w = 0; w < 8; ++w) total += s_w[buf][w];
    if (total >= remaining) prefix |= (1u << bit);
    else remaining -= total;
  }

  if (K > 0) {
    const float t = __uint_as_float(prefix);
    double sg = 0.0;
    int cg = 0;
    #pragma unroll
    for (int k = 0; k < 48; ++k) {
      const float f = __uint_as_float(vals[k]);
      if (f > t) { sg += (double)f; cg++; }
    }
    #pragma unroll
    for (int m = 32; m >= 1; m >>= 1) {
      sg += __shfl_xor(sg, m, 64);
      cg += __shfl_xor(cg, m, 64);
    }
    __shared__ double s_sd[8];
    __shared__ int s_sc[8];
    const int wid = tid >> 6;
    if ((tid & 63) == 0) { s_sd[wid] = sg; s_sc[wid] = cg; }
    __syncthreads();
    if (tid == 0) {
      double S = 0.0;
      int C = 0;
      for (int w = 0; w < 8; ++w) { S += s_sd[w]; C += s_sc[w]; }
      S += (double)(K - C) * (double)t;
      atomicAdd(&acc[2], S);
    }
  }

  // ---- last block finalizes ---------------------------------------------
  __shared__ int s_last;
  __syncthreads();
  if (tid == 0) {
    __threadfence();
    s_last = (atomicAdd(done, 1) == NB - 1) ? 1 : 0;
  }
  __syncthreads();
  if (s_last && tid < 64) {
    int n = 0;
    float L = 0.0f, C = 0.0f;
    if (tid < NB) { n = num_pos[tid]; L = accLb[tid]; C = accCb[tid]; }
    #pragma unroll
    for (int m = 32; m >= 1; m >>= 1) {
      n += __shfl_xor(n, m, 64);
      L += __shfl_xor(L, m, 64);
      C += __shfl_xor(C, m, 64);
    }
    if (tid == 0) {
      const double S = atomicAdd(&acc[2], 0.0);  // coherent read
      const double Nf = (double)n;
      out[0] = (float)((double)L / Nf);
      out[1] = (float)(((double)C + S) / Nf);
    }
  }
}

extern "C" void kernel_launch(void* const* d_in, const int* in_sizes, int n_in,
                              void* d_out, int out_size, void* d_ws, size_t ws_size,
                              hipStream_t stream) {
  const float* loc     = (const float*)d_in[0];
  const float* conf    = (const float*)d_in[1];
  const float* priors  = (const float*)d_in[2];
  const float* targets = (const float*)d_in[3];
  float* out = (float*)d_out;

  char* ws = (char*)d_ws;
  double* acc   = (double*)ws;
  int* num_pos  = (int*)(ws + 32);
  float* accLb  = (float*)(ws + 160);
  float* accCb  = (float*)(ws + 288);
  int* done     = (int*)(ws + 416);
  unsigned long long* bpc = (unsigned long long*)(ws + 424);
  const size_t hdr = 424 + (size_t)NB * NO * NCH * 8;   // 307624
  float* mine  = (float*)(ws + hdr);

  dim3 gA(NCH, NB);
  kA<<<gA, 256, 0, stream>>>(priors, targets, bpc,
                             acc, num_pos, accLb, accCb, done);

  dim3 gM((NP + 255) / 256, NB);
  kMS<<<gM, 256, 0, stream>>>(loc, conf, priors, targets, bpc,
                              mine, num_pos, accLb, accCb);

  kD<<<NB, 512, 0, stream>>>(mine, num_pos, acc, done, accLb, accCb, out);
}

// Round 11
// 142.785 us; speedup vs baseline: 1.7756x; 1.0786x over previous
//
#include <hip/hip_runtime.h>

#define NB 32
#define NP 24564
#define NO 50
#define NC 81
#define THR 0.5f
#define KA_CHUNK 1024
#define NCH 24   // ceil(NP / KA_CHUNK)

__device__ __forceinline__ float rl_f(float v, int j) {
  return __uint_as_float((unsigned)__builtin_amdgcn_readlane((int)__float_as_uint(v), j));
}
__device__ __forceinline__ float bp_f(float v, int j4) {
  return __uint_as_float((unsigned)__builtin_amdgcn_ds_bpermute(j4, (int)__float_as_uint(v)));
}

// ws: acc dbl[4]@0 | num_pos i32[32]@32 | accLb f[32]@160 | accCb f[32]@288
//     done i32@416 | bpc u64[NB*NO*NCH]@424 | hdr | mine f[NB*NP]

// ---------------- Kernel A: per-truth per-chunk best prior + init ----------
__global__ __launch_bounds__(256) void kA(
    const float* __restrict__ priors, const float* __restrict__ targets,
    unsigned long long* __restrict__ bpc,
    double* __restrict__ acc, int* __restrict__ num_pos,
    float* __restrict__ accLb, float* __restrict__ accCb,
    int* __restrict__ done) {
  __shared__ float4 s_pf[KA_CHUNK];
  __shared__ float s_t[NO * 5];
  __shared__ unsigned long long s_bp[256];
  const int b = blockIdx.y;
  const int tid = threadIdx.x;
  const int base = blockIdx.x * KA_CHUNK;

  if (blockIdx.x == 0 && b == 0) {
    if (tid < 4) acc[tid] = 0.0;
    else if (tid >= 32 && tid < 64) num_pos[tid - 32] = 0;
    else if (tid >= 64 && tid < 96) accLb[tid - 64] = 0.0f;
    else if (tid >= 96 && tid < 128) accCb[tid - 96] = 0.0f;
    else if (tid == 128) *done = 0;
  }

  for (int i = tid; i < NO * 5; i += 256) s_t[i] = targets[b * NO * 5 + i];

  #pragma unroll
  for (int k = 0; k < KA_CHUNK / 256; ++k) {
    const int p = base + k * 256 + tid;
    float4 pf;
    if (p < NP) {
      const float4 pr = ((const float4*)priors)[p];
      pf = make_float4(pr.x - pr.z * 0.5f, pr.y - pr.w * 0.5f,
                       pr.x + pr.z * 0.5f, pr.y + pr.w * 0.5f);
    } else {
      pf = make_float4(3.0f, 3.0f, 3.0f, 3.0f);  // degenerate: IoU == 0
    }
    s_pf[k * 256 + tid] = pf;
  }
  __syncthreads();

  const int wv = tid >> 6;
  const int lane = tid & 63;
  unsigned long long best = 0ull;
  if (lane < NO) {
    const float tx1 = s_t[lane * 5 + 0], ty1 = s_t[lane * 5 + 1];
    const float tx2 = s_t[lane * 5 + 2], ty2 = s_t[lane * 5 + 3];
    const float area_a = (tx2 - tx1) * (ty2 - ty1);
    const int i0 = wv * 256;
    #pragma unroll 8
    for (int i = 0; i < 256; ++i) {
      const float4 q = s_pf[i0 + i];
      const float wx = fmaxf(fminf(q.z, tx2) - fmaxf(q.x, tx1), 0.0f);
      const float wy = fmaxf(fminf(q.w, ty2) - fmaxf(q.y, ty1), 0.0f);
      const float inter = wx * wy;
      const float ab = (q.z - q.x) * (q.w - q.y);
      const float iou = __fdividef(inter, area_a + ab - inter);
      const unsigned p = (unsigned)(base + i0 + i);
      const unsigned long long pk =
          (((unsigned long long)__float_as_uint(iou)) << 32) |
          (unsigned long long)(0xFFFFFFFFu - p);
      if (pk > best) best = pk;
    }
  }
  s_bp[tid] = best;
  __syncthreads();
  if (tid < NO) {
    unsigned long long m = s_bp[tid];
    unsigned long long v = s_bp[64 + tid];  if (v > m) m = v;
    v = s_bp[128 + tid];                    if (v > m) m = v;
    v = s_bp[192 + tid];                    if (v > m) m = v;
    bpc[(size_t)(b * NO + tid) * NCH + blockIdx.x] = m;
  }
}

// ---------------- Kernel MS: match + pipelined lse + smooth-L1 -------------
// grid (96, NB), 256 thr; wave owns 64 rows. lse software-pipelined depth 6:
// prologue issues 6 phases' loads; match-loop compute hides their latency;
// consume loop issues ph+6 before consuming ph (all indices compile-time).
__global__ __launch_bounds__(256) void kMS(
    const float* __restrict__ loc, const float* __restrict__ conf,
    const float* __restrict__ priors, const float* __restrict__ targets,
    const unsigned long long* __restrict__ bpc,
    float* __restrict__ mine, int* __restrict__ num_pos,
    float* __restrict__ accLb, float* __restrict__ accCb) {
  __shared__ float s_s[256];
  __shared__ int s_tpb[NO];
  __shared__ float sLw[4], sCw[4];
  __shared__ int sNw[4];
  const int tid = threadIdx.x;
  const int lane = tid & 63;
  const int b = blockIdx.y;
  const int rowbase = blockIdx.x * 256 + (tid & 192);
  const int p = rowbase + lane;
  const bool valid = (p < NP);
  const int pc = valid ? p : NP - 1;
  const size_t grow = (size_t)b * NP + pc;
  const float* tb = targets + (size_t)b * (NO * 5);

  // phase 0: reduce 24 chunk slots per truth -> global-best prior per truth
  if (tid < NO) {
    const unsigned long long* sl = bpc + (size_t)(b * NO + tid) * NCH;
    unsigned long long m = 0ull;
    #pragma unroll
    for (int c = 0; c < NCH; ++c) {
      const unsigned long long v = sl[c];
      if (v > m) m = v;
    }
    s_tpb[tid] = (int)(0xFFFFFFFFu - (unsigned)(m & 0xFFFFFFFFull));
  }

  // lane l (<50) holds truth l in registers
  float ttx1 = 3.f, tty1 = 3.f, ttx2 = 3.f, tty2 = 3.f, tar = 0.f, tlab = 0.f;
  if (lane < NO) {
    ttx1 = tb[lane * 5 + 0]; tty1 = tb[lane * 5 + 1];
    ttx2 = tb[lane * 5 + 2]; tty2 = tb[lane * 5 + 3];
    tlab = tb[lane * 5 + 4];
    tar = (ttx2 - ttx1) * (tty2 - tty1);
  }
  const float4 pr = ((const float4*)priors)[pc];
  const float4 ldv = ((const float4*)loc)[grow];
  const float px1 = pr.x - pr.z * 0.5f, py1 = pr.y - pr.w * 0.5f;
  const float px2 = pr.x + pr.z * 0.5f, py2 = pr.y + pr.w * 0.5f;
  const float areab = (px2 - px1) * (py2 - py1);
  __syncthreads();
  const int tpb = (lane < NO) ? s_tpb[lane] : -1;

  // ---- lse pipeline setup ----------------------------------------------
  const int l16 = lane & 15;
  const int g4 = (lane >> 4) & 3;
  const int c0 = (4 - g4) & 3;           // 16B-aligned float4 base
  const int tc = (l16 < c0) ? l16 : (c0 + 64 + (l16 - c0));
  const float* cb = conf + (size_t)b * NP * NC;

  float4 v4[8];
  float vta[8], v80[8];

  #define KMS_ROWP(ph) (cb + (size_t)((rowbase + (ph) * 4 + g4) < NP \
      ? (rowbase + (ph) * 4 + g4) : (NP - 1)) * NC)
  #define KMS_ISSUE(ph) { const float* rp_ = KMS_ROWP(ph);            \
      v4[(ph) & 7] = *(const float4*)(rp_ + c0 + 4 * l16);            \
      vta[(ph) & 7] = rp_[tc]; v80[(ph) & 7] = rp_[80]; }

  // prologue: 6 phases in flight; match compute below hides their latency
  KMS_ISSUE(0) KMS_ISSUE(1) KMS_ISSUE(2)
  KMS_ISSUE(3) KMS_ISSUE(4) KMS_ISSUE(5)
  __builtin_amdgcn_sched_barrier(0);

  // ---- match: memory-free 50-truth loop --------------------------------
  float bv = -1.0f;
  int bj = 0;
  #pragma unroll 2
  for (int j = 0; j < NO; ++j) {
    const float x1 = rl_f(ttx1, j), y1 = rl_f(tty1, j);
    const float x2 = rl_f(ttx2, j), y2 = rl_f(tty2, j);
    const float aa = rl_f(tar, j);
    const float wx = fmaxf(fminf(x2, px2) - fmaxf(x1, px1), 0.0f);
    const float wy = fmaxf(fminf(y2, py2) - fmaxf(y1, py1), 0.0f);
    const float inter = wx * wy;
    const float iou = __fdividef(inter, aa + areab - inter);
    if (iou > bv) { bv = iou; bj = j; }   // first-max tie-break
  }

  // ---- forced-match override via ballot scan (rare) --------------------
  int ovj = -1;
  unsigned long long M = __ballot((lane < NO) && ((unsigned)(tpb - rowbase) < 64u));
  while (M) {
    const int l = __ffsll((long long)M) - 1;
    M &= M - 1;
    const int r = __builtin_amdgcn_readlane(tpb, l) - rowbase;
    if (lane == r) ovj = l;              // ascending l -> last j wins
  }
  const int jm = (ovj >= 0) ? ovj : bj;
  const bool pos = valid && ((ovj >= 0) || (bv >= THR));
  const int j4 = jm << 2;
  const float lab = bp_f(tlab, j4);      // unconditional: all lanes active
  const float mx1 = bp_f(ttx1, j4), my1 = bp_f(tty1, j4);
  const float mx2 = bp_f(ttx2, j4), my2 = bp_f(tty2, j4);
  const int conft = pos ? ((int)lab + 1) : 0;

  // ---- smooth-L1 (positives only) --------------------------------------
  float sl1 = 0.0f;
  if (pos) {
    const float gcx = __fdividef((mx1 + mx2) * 0.5f - pr.x, 0.1f * pr.z);
    const float gcy = __fdividef((my1 + my2) * 0.5f - pr.y, 0.1f * pr.w);
    const float gw = __logf(__fdividef(mx2 - mx1, pr.z)) * 5.0f;
    const float gh = __logf(__fdividef(my2 - my1, pr.w)) * 5.0f;
    const float d0 = ldv.x - gcx, d1 = ldv.y - gcy;
    const float d2 = ldv.z - gw, d3 = ldv.w - gh;
    #pragma unroll
    for (int q = 0; q < 4; ++q) {
      const float d = (q == 0) ? d0 : (q == 1) ? d1 : (q == 2) ? d2 : d3;
      const float a = fabsf(d);
      sl1 += (a < 1.0f) ? 0.5f * d * d : a - 0.5f;
    }
  }

  // ---- lse consume: fully unrolled, issue ph+6 before consuming ph ------
  #pragma unroll
  for (int ph = 0; ph < 16; ++ph) {
    if (ph + 6 < 16) KMS_ISSUE(ph + 6)
    const float4 v = v4[ph & 7];
    float s = __expf(v.x) + __expf(v.y) + __expf(v.z) + __expf(v.w);
    s += __expf(vta[ph & 7]);
    const float e80 = __expf(v80[ph & 7]);
    s += (l16 == 0) ? e80 : 0.0f;
    s += __shfl_xor(s, 1, 64);
    s += __shfl_xor(s, 2, 64);
    s += __shfl_xor(s, 4, 64);
    s += __shfl_xor(s, 8, 64);
    if (l16 == 0) s_s[(tid & 192) + ph * 4 + g4] = s;
  }
  const float myS = s_s[tid];            // wave-local; lgkmcnt ordered

  const float gval = conf[grow * NC + conft];
  const float lca = __logf(myS) - gval;

  float sumL = 0.0f, sumC = 0.0f;
  int cnt = 0;
  if (valid) {
    mine[grow] = pos ? 0.0f : fmaxf(lca, 0.0f);
    if (pos) { cnt = 1; sumC = lca; sumL = sl1; }
  }

  // ---- wave + block reduce, one atomic set per block --------------------
  #pragma unroll
  for (int m = 1; m <= 32; m <<= 1) {
    sumL += __shfl_xor(sumL, m, 64);
    sumC += __shfl_xor(sumC, m, 64);
    cnt  += __shfl_xor(cnt, m, 64);
  }
  const int w = tid >> 6;
  if (lane == 0) { sLw[w] = sumL; sCw[w] = sumC; sNw[w] = cnt; }
  __syncthreads();
  if (tid == 0) {
    const float L = sLw[0] + sLw[1] + sLw[2] + sLw[3];
    const float C = sCw[0] + sCw[1] + sCw[2] + sCw[3];
    const int n = sNw[0] + sNw[1] + sNw[2] + sNw[3];
    if (L != 0.0f) atomicAdd(&accLb[b], L);
    if (C != 0.0f) atomicAdd(&accCb[b], C);
    if (n) atomicAdd(&num_pos[b], n);
  }
}

// ---------------- Kernel D: top-K radix select + fused finalize ------------
__global__ __launch_bounds__(512) void kD(
    const float* __restrict__ mine, const int* __restrict__ num_pos,
    double* __restrict__ acc, int* __restrict__ done,
    const float* __restrict__ accLb, const float* __restrict__ accCb,
    float* __restrict__ out) {
  const int b = blockIdx.x;
  const int tid = threadIdx.x;
  const uint4* vb4 = (const uint4*)(mine + (size_t)b * NP);

  unsigned vals[48];
  #pragma unroll
  for (int k = 0; k < 12; ++k) {
    const int i = tid + k * 512;
    uint4 q = make_uint4(0u, 0u, 0u, 0u);
    if (i < NP / 4) q = vb4[i];          // NP/4 == 6141 exactly
    vals[4 * k + 0] = q.x; vals[4 * k + 1] = q.y;
    vals[4 * k + 2] = q.z; vals[4 * k + 3] = q.w;
  }

  const int K = min(3 * num_pos[b], NP - 1);

  __shared__ int s_w[2][8];
  unsigned prefix = 0u;
  int remaining = K;

  for (int bit = 30; bit >= 0; --bit) {
    const unsigned want = (prefix >> bit) | 1u;
    int cnt = 0;
    #pragma unroll
    for (int k = 0; k < 48; ++k) cnt += ((vals[k] >> bit) == want) ? 1 : 0;
    #pragma unroll
    for (int m = 32; m >= 1; m >>= 1) cnt += __shfl_xor(cnt, m, 64);
    const int buf = bit & 1;
    if ((tid & 63) == 0) s_w[buf][tid >> 6] = cnt;
    __syncthreads();
    int total = 0;
    #pragma unroll
    for (int w = 0; w < 8; ++w) total += s_w[buf][w];
    if (total >= remaining) prefix |= (1u << bit);
    else remaining -= total;
  }

  if (K > 0) {
    const float t = __uint_as_float(prefix);
    double sg = 0.0;
    int cg = 0;
    #pragma unroll
    for (int k = 0; k < 48; ++k) {
      const float f = __uint_as_float(vals[k]);
      if (f > t) { sg += (double)f; cg++; }
    }
    #pragma unroll
    for (int m = 32; m >= 1; m >>= 1) {
      sg += __shfl_xor(sg, m, 64);
      cg += __shfl_xor(cg, m, 64);
    }
    __shared__ double s_sd[8];
    __shared__ int s_sc[8];
    const int wid = tid >> 6;
    if ((tid & 63) == 0) { s_sd[wid] = sg; s_sc[wid] = cg; }
    __syncthreads();
    if (tid == 0) {
      double S = 0.0;
      int C = 0;
      for (int w = 0; w < 8; ++w) { S += s_sd[w]; C += s_sc[w]; }
      S += (double)(K - C) * (double)t;
      atomicAdd(&acc[2], S);
    }
  }

  // ---- last block finalizes ---------------------------------------------
  __shared__ int s_last;
  __syncthreads();
  if (tid == 0) {
    __threadfence();
    s_last = (atomicAdd(done, 1) == NB - 1) ? 1 : 0;
  }
  __syncthreads();
  if (s_last && tid < 64) {
    int n = 0;
    float L = 0.0f, C = 0.0f;
    if (tid < NB) { n = num_pos[tid]; L = accLb[tid]; C = accCb[tid]; }
    #pragma unroll
    for (int m = 32; m >= 1; m >>= 1) {
      n += __shfl_xor(n, m, 64);
      L += __shfl_xor(L, m, 64);
      C += __shfl_xor(C, m, 64);
    }
    if (tid == 0) {
      const double S = atomicAdd(&acc[2], 0.0);  // coherent read
      const double Nf = (double)n;
      out[0] = (float)((double)L / Nf);
      out[1] = (float)(((double)C + S) / Nf);
    }
  }
}

extern "C" void kernel_launch(void* const* d_in, const int* in_sizes, int n_in,
                              void* d_out, int out_size, void* d_ws, size_t ws_size,
                              hipStream_t stream) {
  const float* loc     = (const float*)d_in[0];
  const float* conf    = (const float*)d_in[1];
  const float* priors  = (const float*)d_in[2];
  const float* targets = (const float*)d_in[3];
  float* out = (float*)d_out;

  char* ws = (char*)d_ws;
  double* acc   = (double*)ws;
  int* num_pos  = (int*)(ws + 32);
  float* accLb  = (float*)(ws + 160);
  float* accCb  = (float*)(ws + 288);
  int* done     = (int*)(ws + 416);
  unsigned long long* bpc = (unsigned long long*)(ws + 424);
  const size_t hdr = 424 + (size_t)NB * NO * NCH * 8;   // 307624
  float* mine  = (float*)(ws + hdr);

  dim3 gA(NCH, NB);
  kA<<<gA, 256, 0, stream>>>(priors, targets, bpc,
                             acc, num_pos, accLb, accCb, done);

  dim3 gM((NP + 255) / 256, NB);
  kMS<<<gM, 256, 0, stream>>>(loc, conf, priors, targets, bpc,
                              mine, num_pos, accLb, accCb);

  kD<<<NB, 512, 0, stream>>>(mine, num_pos, acc, done, accLb, accCb, out);
}